// Round 5
// baseline (508.551 us; speedup 1.0000x reference)
//
#include <hip/hip_runtime.h>
#include <cstdint>
#include <cstddef>

#define T_TOK 2048
#define H_DIM 2048
#define S_LEN 1024
#define HD 128
#define NH 16
#define NKV 4
#define QKV_O 3072
#define MM 512
#define EPS 1e-6f
#define ATT_SCALE 0.08838834764831845f  // 128^-0.5

typedef __bf16 bf16x8 __attribute__((ext_vector_type(8)));
typedef __bf16 bf16x4 __attribute__((ext_vector_type(4)));
typedef float  f32x4  __attribute__((ext_vector_type(4)));

__device__ __forceinline__ __bf16 f2bf(float f) {
  unsigned u = __builtin_bit_cast(unsigned, f);
  u += 0x7fffu + ((u >> 16) & 1u);           // RNE; inputs are finite
  unsigned short h = (unsigned short)(u >> 16);
  return __builtin_bit_cast(__bf16, h);
}
__device__ __forceinline__ f32x4 fzero4() {
  f32x4 z; z[0] = 0.f; z[1] = 0.f; z[2] = 0.f; z[3] = 0.f; return z;
}
// async global->LDS, 16B per lane.
__device__ __forceinline__ void gld16(const __bf16* g, __bf16* l) {
  __builtin_amdgcn_global_load_lds(
      (const __attribute__((address_space(1))) unsigned int*)g,
      (__attribute__((address_space(3))) unsigned int*)l, 16, 0, 0);
}

// ---------------------------------------------------------------------------
// Weight fp32 -> bf16: now ONLY wqkv + wdense (10.5M elems). MoE weights are
// converted in-GEMM (R4: wconv rate pinned at ~3.4 TB/s across 3 layouts ->
// cut bytes instead; 73% of them moved into gateup/down staging).
// ---------------------------------------------------------------------------
__global__ __launch_bounds__(256) void wconv_k(
    const float* __restrict__ s0, const float* __restrict__ s1,
    __bf16* __restrict__ dst) {
  size_t e = ((size_t)blockIdx.x * 256 + threadIdx.x) * 16;
  const size_t E0 = 6291456;   // wqkv elems; then wdense
  const float* src; size_t base;
  if (e < E0) { src = s0; base = 0; }
  else        { src = s1; base = E0; }
  const float4* sp = (const float4*)(src + (e - base));
  float4 f0 = sp[0], f1 = sp[1], f2 = sp[2], f3 = sp[3];
  bf16x8 o0, o1;
  o0[0] = f2bf(f0.x); o0[1] = f2bf(f0.y); o0[2] = f2bf(f0.z); o0[3] = f2bf(f0.w);
  o0[4] = f2bf(f1.x); o0[5] = f2bf(f1.y); o0[6] = f2bf(f1.z); o0[7] = f2bf(f1.w);
  o1[0] = f2bf(f2.x); o1[1] = f2bf(f2.y); o1[2] = f2bf(f2.z); o1[3] = f2bf(f2.w);
  o1[4] = f2bf(f3.x); o1[5] = f2bf(f3.y); o1[6] = f2bf(f3.z); o1[7] = f2bf(f3.w);
  *(bf16x8*)(dst + e) = o0;
  *(bf16x8*)(dst + e + 8) = o1;
}

// ---------------------------------------------------------------------------
// RMSNorm over H=2048, fp32 in -> bf16 out. One block (256 thr) per token.
// ---------------------------------------------------------------------------
__global__ __launch_bounds__(256) void rmsnorm_k(const float* __restrict__ X,
                                                 const float* __restrict__ W,
                                                 __bf16* __restrict__ Y) {
  int t = blockIdx.x;
  int tid = threadIdx.x, lane = tid & 63, wid = tid >> 6;
  const float4* row = (const float4*)(X + (size_t)t * H_DIM);
  float4 v0 = row[tid], v1 = row[tid + 256];
  float ss = v0.x*v0.x + v0.y*v0.y + v0.z*v0.z + v0.w*v0.w
           + v1.x*v1.x + v1.y*v1.y + v1.z*v1.z + v1.w*v1.w;
  #pragma unroll
  for (int m = 1; m <= 32; m <<= 1) ss += __shfl_xor(ss, m, 64);
  __shared__ float red[4];
  if (lane == 0) red[wid] = ss;
  __syncthreads();
  float tot = red[0] + red[1] + red[2] + red[3];
  float sc = rsqrtf(tot * (1.f / H_DIM) + EPS);
  const float4* wp = (const float4*)W;
  float4 w0 = wp[tid], w1 = wp[tid + 256];
  bf16x4 o;
  o[0] = f2bf(v0.x*w0.x*sc); o[1] = f2bf(v0.y*w0.y*sc);
  o[2] = f2bf(v0.z*w0.z*sc); o[3] = f2bf(v0.w*w0.w*sc);
  *(bf16x4*)&Y[(size_t)t*H_DIM + tid*4] = o;
  o[0] = f2bf(v1.x*w1.x*sc); o[1] = f2bf(v1.y*w1.y*sc);
  o[2] = f2bf(v1.z*w1.z*sc); o[3] = f2bf(v1.w*w1.w*sc);
  *(bf16x4*)&Y[(size_t)t*H_DIM + 1024 + tid*4] = o;
}

// ---------------------------------------------------------------------------
// NT GEMM, 64(M) x 128(N) tile, BK=64, dbuf LDS, m97-style staging.
// MODE 0: OB bf16 plain store (ld N)            [qkv]
// MODE 1: C fp32 = acc + resid (ld 2048)        [dense + residual]
// ---------------------------------------------------------------------------
template<int MODE>
__global__ __launch_bounds__(256) void gemm64_nt(
    const __bf16* __restrict__ A, const __bf16* __restrict__ B,
    float* __restrict__ C, __bf16* __restrict__ OB,
    const float* __restrict__ resid, int N, int K) {
  int m0 = blockIdx.y * 64;
  int n0 = blockIdx.x * 128;
  __shared__ __bf16 sA[2][64 * 64];
  __shared__ __bf16 sB[2][128 * 64];
  int tid = threadIdx.x, lane = tid & 63, wid = tid >> 6;
  int quad = lane >> 4, l16 = lane & 15;
  int wm = wid & 1, wn = wid >> 1;

  const __bf16* gA[2]; const __bf16* gB[4];
  #pragma unroll
  for (int i = 0; i < 2; i++) {
    int p = tid + 256 * i;
    int row = p >> 3, sc = p & 7, gc = sc ^ (row & 7);
    gA[i] = A + (size_t)(m0 + row) * K + gc * 8;
  }
  #pragma unroll
  for (int i = 0; i < 4; i++) {
    int p = tid + 256 * i;
    int row = p >> 3, sc = p & 7, gc = sc ^ (row & 7);
    gB[i] = B + (size_t)(n0 + row) * K + gc * 8;
  }
  f32x4 acc[2][4];
  #pragma unroll
  for (int i = 0; i < 2; i++)
    #pragma unroll
    for (int j = 0; j < 4; j++) acc[i][j] = fzero4();

  auto stage = [&](int buf, int k0) {
    #pragma unroll
    for (int i = 0; i < 2; i++)
      gld16(gA[i] + k0, &sA[buf][(tid + 256 * i) * 8]);
    #pragma unroll
    for (int i = 0; i < 4; i++)
      gld16(gB[i] + k0, &sB[buf][(tid + 256 * i) * 8]);
  };
  stage(0, 0);
  int cur = 0;
  for (int k0 = 0; k0 < K; k0 += 64) {
    __syncthreads();
    if (k0 + 64 < K) stage(cur ^ 1, k0 + 64);
    #pragma unroll
    for (int ks = 0; ks < 64; ks += 32) {
      int cb = ks >> 3;
      bf16x8 aF[2], bF[4];
      #pragma unroll
      for (int mt = 0; mt < 2; mt++) {
        int row = wm * 32 + mt * 16 + l16;
        int pos = row * 8 + ((cb + quad) ^ (row & 7));
        aF[mt] = *(const bf16x8*)&sA[cur][pos * 8];
      }
      #pragma unroll
      for (int nt = 0; nt < 4; nt++) {
        int row = wn * 64 + nt * 16 + l16;
        int pos = row * 8 + ((cb + quad) ^ (row & 7));
        bF[nt] = *(const bf16x8*)&sB[cur][pos * 8];
      }
      #pragma unroll
      for (int mt = 0; mt < 2; mt++)
        #pragma unroll
        for (int nt = 0; nt < 4; nt++)
          acc[mt][nt] = __builtin_amdgcn_mfma_f32_16x16x32_bf16(
              aF[mt], bF[nt], acc[mt][nt], 0, 0, 0);
    }
    cur ^= 1;
  }
  #pragma unroll
  for (int mt = 0; mt < 2; mt++) {
    #pragma unroll
    for (int nt = 0; nt < 4; nt++) {
      #pragma unroll
      for (int r = 0; r < 4; r++) {
        int grow = m0 + wm*32 + mt*16 + quad*4 + r;
        int gcol = n0 + wn*64 + nt*16 + l16;
        float val = acc[mt][nt][r];
        if (MODE == 0) {
          OB[(size_t)grow * N + gcol] = f2bf(val);
        } else {
          C[(size_t)grow * H_DIM + gcol] = val + resid[(size_t)grow * H_DIM + gcol];
        }
      }
    }
  }
}

// ---------------------------------------------------------------------------
// Expert down-proj GEMM (128x128 tile, dbuf). grid.z = expert (8 = shared).
// B is fp32 (wed/wsd): reg-staged, cvt->bf16, ds_write late (T14 split) --
// conversion folded out of wconv. A (he bf16) stays global_load_lds.
// ---------------------------------------------------------------------------
__global__ __launch_bounds__(256) void gemm_down(
    const __bf16* __restrict__ A, const float* __restrict__ B,
    const float* __restrict__ B2, __bf16* __restrict__ OB,
    const int* __restrict__ list, const signed char* __restrict__ jsl,
    const int* __restrict__ cnt) {
  int e  = blockIdx.z;
  int ne = (e == 8) ? T_TOK : cnt[e];
  int m0 = blockIdx.y * 128;
  if (m0 >= ne) return;
  int n0 = blockIdx.x * 128;
  const __bf16* Ab = A + (size_t)e * T_TOK * MM;
  const float*  Bb = (e < 8) ? B + (size_t)e * H_DIM * MM : B2;
  const int K = MM;
  __shared__ __bf16 sA[2][128 * 64];
  __shared__ __bf16 sB[2][128 * 64];
  int tid = threadIdx.x, lane = tid & 63, wid = tid >> 6;
  int quad = lane >> 4, l16 = lane & 15;
  int wm = wid & 1, wn = wid >> 1;

  const __bf16* gA[4]; const float* gB[4];
  #pragma unroll
  for (int i = 0; i < 4; i++) {
    int p = tid + 256 * i;
    int row = p >> 3, sc = p & 7, gc = sc ^ (row & 7);
    gA[i] = Ab + (size_t)(m0 + row) * K + gc * 8;
    gB[i] = Bb + (size_t)(n0 + row) * K + gc * 8;
  }
  f32x4 acc[4][4];
  #pragma unroll
  for (int i = 0; i < 4; i++)
    #pragma unroll
    for (int j = 0; j < 4; j++) acc[i][j] = fzero4();

  f32x4 br[4][2];                       // fp32 B regs (32 VGPR)
  auto stageA = [&](int buf, int k0) {
    #pragma unroll
    for (int i = 0; i < 4; i++)
      gld16(gA[i] + k0, &sA[buf][(tid + 256 * i) * 8]);
  };
  auto loadB = [&](int k0) {
    #pragma unroll
    for (int i = 0; i < 4; i++) {
      br[i][0] = *(const f32x4*)(gB[i] + k0);
      br[i][1] = *(const f32x4*)(gB[i] + k0 + 4);
    }
  };
  auto writeB = [&](int buf) {
    #pragma unroll
    for (int i = 0; i < 4; i++) {
      int p = tid + 256 * i;
      bf16x8 o;
      #pragma unroll
      for (int j = 0; j < 4; j++) { o[j] = f2bf(br[i][0][j]); o[j+4] = f2bf(br[i][1][j]); }
      *(bf16x8*)&sB[buf][p * 8] = o;
    }
  };
  stageA(0, 0); loadB(0); writeB(0);
  int cur = 0;
  for (int k0 = 0; k0 < K; k0 += 64) {
    __syncthreads();
    bool nxt = (k0 + 64 < K);
    if (nxt) { stageA(cur ^ 1, k0 + 64); loadB(k0 + 64); }
    #pragma unroll
    for (int ks = 0; ks < 64; ks += 32) {
      int cb = ks >> 3;
      bf16x8 aF[4], bF[4];
      #pragma unroll
      for (int mt = 0; mt < 4; mt++) {
        int row = wm * 64 + mt * 16 + l16;
        int pos = row * 8 + ((cb + quad) ^ (row & 7));
        aF[mt] = *(const bf16x8*)&sA[cur][pos * 8];
      }
      #pragma unroll
      for (int nt = 0; nt < 4; nt++) {
        int row = wn * 64 + nt * 16 + l16;
        int pos = row * 8 + ((cb + quad) ^ (row & 7));
        bF[nt] = *(const bf16x8*)&sB[cur][pos * 8];
      }
      #pragma unroll
      for (int mt = 0; mt < 4; mt++)
        #pragma unroll
        for (int nt = 0; nt < 4; nt++)
          acc[mt][nt] = __builtin_amdgcn_mfma_f32_16x16x32_bf16(
              aF[mt], bF[nt], acc[mt][nt], 0, 0, 0);
    }
    if (nxt) writeB(cur ^ 1);
    cur ^= 1;
  }
  #pragma unroll
  for (int mt = 0; mt < 4; mt++) {
    #pragma unroll
    for (int nt = 0; nt < 4; nt++) {
      #pragma unroll
      for (int r = 0; r < 4; r++) {
        int grow = m0 + wm*64 + mt*16 + quad*4 + r;
        int gcol = n0 + wn*64 + nt*16 + l16;
        if (grow < ne) {
          int tk = list[e * T_TOK + grow];
          int j  = (e == 8) ? 2 : (int)jsl[e * T_TOK + grow];
          OB[((size_t)tk * 3 + j) * H_DIM + gcol] = f2bf(acc[mt][nt][r]);
        }
      }
    }
  }
}

// ---------------------------------------------------------------------------
// Combine: out[t] += buf[t][0] + buf[t][1] + buf[t][2]  (bf16 contributions).
// ---------------------------------------------------------------------------
__global__ __launch_bounds__(256) void combine_k(const __bf16* __restrict__ buf,
                                                 float* __restrict__ out) {
  int t = blockIdx.x, tid = threadIdx.x;
  const __bf16* base = buf + (size_t)t * 3 * H_DIM;
  bf16x8 v0 = *(const bf16x8*)(base + tid * 8);
  bf16x8 v1 = *(const bf16x8*)(base + H_DIM + tid * 8);
  bf16x8 v2 = *(const bf16x8*)(base + 2 * H_DIM + tid * 8);
  float* o = out + (size_t)t * H_DIM + tid * 8;
  float4 a = *(float4*)o, b = *(float4*)(o + 4);
  a.x += (float)v0[0] + (float)v1[0] + (float)v2[0];
  a.y += (float)v0[1] + (float)v1[1] + (float)v2[1];
  a.z += (float)v0[2] + (float)v1[2] + (float)v2[2];
  a.w += (float)v0[3] + (float)v1[3] + (float)v2[3];
  b.x += (float)v0[4] + (float)v1[4] + (float)v2[4];
  b.y += (float)v0[5] + (float)v1[5] + (float)v2[5];
  b.z += (float)v0[6] + (float)v1[6] + (float)v2[6];
  b.w += (float)v0[7] + (float)v1[7] + (float)v2[7];
  *(float4*)o = a; *(float4*)(o + 4) = b;
}

// ---------------------------------------------------------------------------
// Per (token, head): q/k RMSNorm (HD=128) + RoPE, v passthrough; bf16 in/out.
// ---------------------------------------------------------------------------
__global__ __launch_bounds__(256) void rope_k(
    const __bf16* __restrict__ qkv, const float* __restrict__ qlw,
    const float* __restrict__ klw, const float* __restrict__ cosp,
    const float* __restrict__ sinp, __bf16* __restrict__ qb,
    __bf16* __restrict__ kb, __bf16* __restrict__ vb) {
  int bid = blockIdx.x;                 // T_TOK * 6
  int t = bid / 6;
  int head = (bid % 6) * 4 + (threadIdx.x >> 6);
  int b = t >> 10, s = t & 1023;
  int d = threadIdx.x & 63;
  const __bf16* src = qkv + (size_t)t * QKV_O + head * HD;
  float x1 = (float)src[d], x2 = (float)src[d + 64];
  if (head < 20) {
    float ssq = x1*x1 + x2*x2;
    #pragma unroll
    for (int m = 1; m <= 32; m <<= 1) ssq += __shfl_xor(ssq, m, 64);
    float sc = rsqrtf(ssq * (1.f / HD) + EPS);
    const float* w = (head < 16) ? qlw : klw;
    x1 = x1 * sc * w[d];
    x2 = x2 * sc * w[d + 64];
    size_t cb = (size_t)t * HD;
    float c1 = cosp[cb + d], s1 = sinp[cb + d];
    float c2 = cosp[cb + d + 64], s2 = sinp[cb + d + 64];
    float o1 = x1 * c1 - x2 * s1;
    float o2 = x2 * c2 + x1 * s2;
    if (head < 16) {
      __bf16* dst = qb + (((size_t)(b * NH + head)) * S_LEN + s) * HD;
      dst[d] = f2bf(o1); dst[d + 64] = f2bf(o2);
    } else {
      int kv = head - 16;
      __bf16* dst = kb + (((size_t)(b * NKV + kv)) * S_LEN + s) * HD;
      dst[d] = f2bf(o1); dst[d + 64] = f2bf(o2);
    }
  } else {
    int kv = head - 20;
    __bf16* dst = vb + (((size_t)(b * NKV + kv)) * S_LEN + s) * HD;
    dst[d] = src[d]; dst[d + 64] = src[d + 64];
  }
}

// ---------------------------------------------------------------------------
// V transpose: vb [g][s][d] -> vt [g][d][s]  (g = b*NKV+kv), 64x64 tiles.
// ---------------------------------------------------------------------------
__global__ __launch_bounds__(256) void vtrans_k(const __bf16* __restrict__ vb,
                                                __bf16* __restrict__ vt) {
  int s0 = blockIdx.x * 64, d0 = blockIdx.y * 64, g = blockIdx.z;
  __shared__ __bf16 sT[64 * 80];
  int tid = threadIdx.x;
  const __bf16* src = vb + (size_t)g * S_LEN * HD;
  #pragma unroll
  for (int i = 0; i < 2; i++) {
    int p = tid + 256 * i;
    int rs = p >> 3, cc = p & 7;
    bf16x8 v = *(const bf16x8*)(src + (size_t)(s0 + rs) * HD + d0 + cc * 8);
    #pragma unroll
    for (int j = 0; j < 8; j++) sT[(cc * 8 + j) * 80 + rs] = v[j];
  }
  __syncthreads();
  __bf16* dst = vt + (size_t)g * HD * S_LEN;
  #pragma unroll
  for (int i = 0; i < 2; i++) {
    int p = tid + 256 * i;
    int rd = p >> 3, cs = p & 7;
    bf16x8 v = *(const bf16x8*)&sT[rd * 80 + cs * 8];
    *(bf16x8*)(dst + (size_t)(d0 + rd) * S_LEN + s0 + cs * 8) = v;
  }
}

// ---------------------------------------------------------------------------
// Flash attention v2.
// ---------------------------------------------------------------------------
__global__ __launch_bounds__(256) void flash_k(
    const __bf16* __restrict__ qb, const __bf16* __restrict__ kb,
    const __bf16* __restrict__ vt, __bf16* __restrict__ outb) {
  int qt = blockIdx.x, bh = blockIdx.y;
  int b = bh >> 4, h = bh & 15, kv = h >> 2;
  int tid = threadIdx.x, lane = tid & 63, wid = tid >> 6;
  int quad = lane >> 4, l16 = lane & 15;
  __shared__ __bf16 sQ[64 * 128];
  __shared__ __bf16 sKP[64 * 128];
  __shared__ __bf16 sVt[128 * 64];
  __bf16* sK = sKP;
  __bf16* sP = sKP;

  const __bf16* qsrc = qb + (((size_t)(b * NH + h)) * S_LEN + qt * 64) * HD;
  #pragma unroll
  for (int i = 0; i < 4; i++) {
    int p = tid + 256 * i;
    int row = p >> 4, sc = p & 15, gc = sc ^ (row & 7);
    gld16(qsrc + (size_t)row * HD + gc * 8, &sQ[p * 8]);
  }
  const __bf16* kbase  = kb + ((size_t)(b * NKV + kv)) * S_LEN * HD;
  const __bf16* vtbase = vt + ((size_t)(b * NKV + kv)) * HD * S_LEN;
  const __bf16* gK[4]; const __bf16* gV[4];
  #pragma unroll
  for (int i = 0; i < 4; i++) {
    int p = tid + 256 * i;
    int rowk = p >> 4, sck = p & 15, gck = sck ^ (rowk & 7);
    gK[i] = kbase + (size_t)rowk * HD + gck * 8;
    int rowv = p >> 3, scv = p & 7, gcv = scv ^ (rowv & 7);
    gV[i] = vtbase + (size_t)rowv * S_LEN + gcv * 8;
  }
  float mrow[4], lrow[4];
  #pragma unroll
  for (int r = 0; r < 4; r++) { mrow[r] = -__builtin_inff(); lrow[r] = 0.f; }
  f32x4 accO[8];
  #pragma unroll
  for (int i = 0; i < 8; i++) accO[i] = fzero4();

  for (int kt = 0; kt < 16; kt++) {
    __syncthreads();
    #pragma unroll
    for (int i = 0; i < 4; i++) {
      gld16(gK[i] + (size_t)kt * 64 * HD, &sK[(tid + 256 * i) * 8]);
      gld16(gV[i] + kt * 64, &sVt[(tid + 256 * i) * 8]);
    }
    __syncthreads();
    f32x4 accS[4];
    #pragma unroll
    for (int jt = 0; jt < 4; jt++) accS[jt] = fzero4();
    int rowA = wid * 16 + l16;
    #pragma unroll
    for (int ks2 = 0; ks2 < 4; ks2++) {
      int posA = rowA * 16 + ((ks2 * 4 + quad) ^ (rowA & 7));
      bf16x8 aF = *(const bf16x8*)&sQ[posA * 8];
      #pragma unroll
      for (int jt = 0; jt < 4; jt++) {
        int rowB = jt * 16 + l16;
        int posB = rowB * 16 + ((ks2 * 4 + quad) ^ (rowB & 7));
        bf16x8 bF = *(const bf16x8*)&sK[posB * 8];
        accS[jt] = __builtin_amdgcn_mfma_f32_16x16x32_bf16(aF, bF, accS[jt], 0, 0, 0);
      }
    }
    float alpha[4];
    #pragma unroll
    for (int r = 0; r < 4; r++) {
      float mx = -__builtin_inff();
      #pragma unroll
      for (int jt = 0; jt < 4; jt++) {
        accS[jt][r] *= ATT_SCALE;
        mx = fmaxf(mx, accS[jt][r]);
      }
      #pragma unroll
      for (int m = 1; m <= 8; m <<= 1) mx = fmaxf(mx, __shfl_xor(mx, m, 64));
      float mn = fmaxf(mrow[r], mx);
      float al = __expf(mrow[r] - mn);
      float rs = 0.f;
      #pragma unroll
      for (int jt = 0; jt < 4; jt++) {
        float p = __expf(accS[jt][r] - mn);
        accS[jt][r] = p;
        rs += p;
      }
      #pragma unroll
      for (int m = 1; m <= 8; m <<= 1) rs += __shfl_xor(rs, m, 64);
      lrow[r] = lrow[r] * al + rs;
      mrow[r] = mn;
      alpha[r] = al;
    }
    #pragma unroll
    for (int nt = 0; nt < 8; nt++)
      #pragma unroll
      for (int r = 0; r < 4; r++) accO[nt][r] *= alpha[r];
    __syncthreads();
    #pragma unroll
    for (int jt = 0; jt < 4; jt++)
      #pragma unroll
      for (int r = 0; r < 4; r++)
        sP[(wid * 16 + quad * 4 + r) * 72 + jt * 16 + l16] = f2bf(accS[jt][r]);
    __syncthreads();
    #pragma unroll
    for (int ks2 = 0; ks2 < 2; ks2++) {
      bf16x8 aF = *(const bf16x8*)&sP[(wid * 16 + l16) * 72 + ks2 * 32 + quad * 8];
      #pragma unroll
      for (int nt = 0; nt < 8; nt++) {
        int rowB = nt * 16 + l16;
        int posB = rowB * 8 + ((ks2 * 4 + quad) ^ (rowB & 7));
        bf16x8 bF = *(const bf16x8*)&sVt[posB * 8];
        accO[nt] = __builtin_amdgcn_mfma_f32_16x16x32_bf16(aF, bF, accO[nt], 0, 0, 0);
      }
    }
  }
  #pragma unroll
  for (int nt = 0; nt < 8; nt++) {
    #pragma unroll
    for (int r = 0; r < 4; r++) {
      int srow = qt * 64 + wid * 16 + quad * 4 + r;
      float val = accO[nt][r] / lrow[r];
      outb[((size_t)(b * S_LEN + srow)) * H_DIM + h * HD + nt * 16 + l16] = f2bf(val);
    }
  }
}

// ---------------------------------------------------------------------------
// Router v2: 256 thr/token, float4-vectorized, wave+LDS reduce.
// ---------------------------------------------------------------------------
__global__ __launch_bounds__(256) void router_k(
    const float* __restrict__ hid, const float* __restrict__ ln2w,
    const float* __restrict__ gw, const float* __restrict__ gb,
    int* __restrict__ cnt, int* __restrict__ list, float* __restrict__ wsl,
    signed char* __restrict__ jsl) {
  int t = blockIdx.x;
  int tid = threadIdx.x, lane = tid & 63, wid = tid >> 6;
  const float4* row = (const float4*)(hid + (size_t)t * H_DIM);
  float4 v0 = row[tid], v1 = row[tid + 256];
  float ss = v0.x*v0.x + v0.y*v0.y + v0.z*v0.z + v0.w*v0.w
           + v1.x*v1.x + v1.y*v1.y + v1.z*v1.z + v1.w*v1.w;
  #pragma unroll
  for (int m = 1; m <= 32; m <<= 1) ss += __shfl_xor(ss, m, 64);
  __shared__ float red[4];
  __shared__ float lred[4][8];
  if (lane == 0) red[wid] = ss;
  __syncthreads();
  float tot = red[0] + red[1] + red[2] + red[3];
  float sc = rsqrtf(tot * (1.f / H_DIM) + EPS);
  const float4* wp = (const float4*)ln2w;
  float4 w0 = wp[tid], w1 = wp[tid + 256];
  float x0 = v0.x*w0.x*sc, x1 = v0.y*w0.y*sc, x2 = v0.z*w0.z*sc, x3 = v0.w*w0.w*sc;
  float x4 = v1.x*w1.x*sc, x5 = v1.y*w1.y*sc, x6 = v1.z*w1.z*sc, x7 = v1.w*w1.w*sc;
  float pe[8];
  #pragma unroll
  for (int e = 0; e < 8; e++) {
    const float4* gp = (const float4*)(gw + (size_t)e * H_DIM);
    float4 g0 = gp[tid], g1 = gp[tid + 256];
    float d = x0*g0.x + x1*g0.y + x2*g0.z + x3*g0.w
            + x4*g1.x + x5*g1.y + x6*g1.z + x7*g1.w;
    #pragma unroll
    for (int m = 1; m <= 32; m <<= 1) d += __shfl_xor(d, m, 64);
    pe[e] = d;
  }
  if (lane == 0) {
    #pragma unroll
    for (int e = 0; e < 8; e++) lred[wid][e] = pe[e];
  }
  __syncthreads();
  if (tid == 0) {
    float s[8], sb[8];
    #pragma unroll
    for (int e = 0; e < 8; e++) {
      float lg = lred[0][e] + lred[1][e] + lred[2][e] + lred[3][e];
      s[e] = 1.f / (1.f + __expf(-lg));
      sb[e] = s[e] + gb[e];
    }
    float gs[4];
    #pragma unroll
    for (int g = 0; g < 4; g++) gs[g] = sb[2 * g] + sb[2 * g + 1];
    int g1 = 0;
    for (int g = 1; g < 4; g++) if (gs[g] > gs[g1]) g1 = g;
    int g2 = -1;
    for (int g = 0; g < 4; g++) if (g != g1 && (g2 < 0 || gs[g] > gs[g2])) g2 = g;
    unsigned emask = (3u << (2 * g1)) | (3u << (2 * g2));
    int e1 = -1;
    for (int e = 0; e < 8; e++) if (((emask >> e) & 1u) && (e1 < 0 || sb[e] > sb[e1])) e1 = e;
    int e2 = -1;
    for (int e = 0; e < 8; e++) if (((emask >> e) & 1u) && e != e1 && (e2 < 0 || sb[e] > sb[e2])) e2 = e;
    float w1s = s[e1], w2s = s[e2];
    float dn = w1s + w2s + 1e-20f;
    w1s /= dn; w2s /= dn;   // RSF = 1.0
    int p1 = atomicAdd(&cnt[e1], 1);
    list[e1 * T_TOK + p1] = t; wsl[e1 * T_TOK + p1] = w1s; jsl[e1 * T_TOK + p1] = 0;
    int p2 = atomicAdd(&cnt[e2], 1);
    list[e2 * T_TOK + p2] = t; wsl[e2 * T_TOK + p2] = w2s; jsl[e2 * T_TOK + p2] = 1;
    list[8 * T_TOK + t] = t; wsl[8 * T_TOK + t] = 1.f;   // shared expert
  }
}

// ---------------------------------------------------------------------------
// Gathered gate+up GEMM, fused silu-mul + weight fold. B (gate/up weights)
// now fp32: reg-staged + cvt + late ds_write (T14). A stays global_load_lds.
// ---------------------------------------------------------------------------
__global__ __launch_bounds__(256) void gemm_gateup(
    const __bf16* __restrict__ X, const float* __restrict__ weg,
    const float* __restrict__ weu, const float* __restrict__ wsg,
    const float* __restrict__ wsu, const int* __restrict__ list,
    const float* __restrict__ wsl, const int* __restrict__ cnt,
    __bf16* __restrict__ he) {
  int e = blockIdx.z;
  int ne = (e == 8) ? T_TOK : cnt[e];
  int m0 = blockIdx.y * 128;
  if (m0 >= ne) return;
  int n0 = blockIdx.x * 64;
  const float* bg = (e < 8) ? weg + (size_t)e * MM * H_DIM : wsg;
  const float* bu = (e < 8) ? weu + (size_t)e * MM * H_DIM : wsu;
  const int* lst = list + e * T_TOK;
  __shared__ __bf16 sA[2][128 * 64];
  __shared__ __bf16 sBg[2][64 * 64];
  __shared__ __bf16 sBu[2][64 * 64];
  int tid = threadIdx.x, lane = tid & 63, wid = tid >> 6;
  int quad = lane >> 4, l16 = lane & 15;

  const __bf16* gA[4]; const float* gBg[2]; const float* gBu[2];
  #pragma unroll
  for (int i = 0; i < 4; i++) {
    int p = tid + 256 * i;
    int row = p >> 3, sc = p & 7, gc = sc ^ (row & 7);
    int r = m0 + row; if (r >= ne) r = ne - 1;
    int tk = lst[r];
    gA[i] = X + (size_t)tk * H_DIM + gc * 8;
  }
  #pragma unroll
  for (int i = 0; i < 2; i++) {
    int p = tid + 256 * i;
    int row = p >> 3, sc = p & 7, gc = sc ^ (row & 7);
    gBg[i] = bg + (size_t)(n0 + row) * H_DIM + gc * 8;
    gBu[i] = bu + (size_t)(n0 + row) * H_DIM + gc * 8;
  }
  f32x4 ag[2][4], au[2][4];
  #pragma unroll
  for (int i = 0; i < 2; i++)
    #pragma unroll
    for (int j = 0; j < 4; j++) { ag[i][j] = fzero4(); au[i][j] = fzero4(); }

  f32x4 bgr[2][2], bur[2][2];           // fp32 B regs (32 VGPR)
  auto stageA = [&](int buf, int k0) {
    #pragma unroll
    for (int i = 0; i < 4; i++)
      gld16(gA[i] + k0, &sA[buf][(tid + 256 * i) * 8]);
  };
  auto loadB = [&](int k0) {
    #pragma unroll
    for (int i = 0; i < 2; i++) {
      bgr[i][0] = *(const f32x4*)(gBg[i] + k0);
      bgr[i][1] = *(const f32x4*)(gBg[i] + k0 + 4);
      bur[i][0] = *(const f32x4*)(gBu[i] + k0);
      bur[i][1] = *(const f32x4*)(gBu[i] + k0 + 4);
    }
  };
  auto writeB = [&](int buf) {
    #pragma unroll
    for (int i = 0; i < 2; i++) {
      int p = tid + 256 * i;
      bf16x8 og, ou;
      #pragma unroll
      for (int j = 0; j < 4; j++) {
        og[j] = f2bf(bgr[i][0][j]); og[j+4] = f2bf(bgr[i][1][j]);
        ou[j] = f2bf(bur[i][0][j]); ou[j+4] = f2bf(bur[i][1][j]);
      }
      *(bf16x8*)&sBg[buf][p * 8] = og;
      *(bf16x8*)&sBu[buf][p * 8] = ou;
    }
  };
  stageA(0, 0); loadB(0); writeB(0);
  int cur = 0;
  for (int k0 = 0; k0 < H_DIM; k0 += 64) {
    __syncthreads();
    bool nxt = (k0 + 64 < H_DIM);
    if (nxt) { stageA(cur ^ 1, k0 + 64); loadB(k0 + 64); }
    #pragma unroll
    for (int ks = 0; ks < 64; ks += 32) {
      int cb = ks >> 3;
      bf16x8 aF[2], gF[4], uF[4];
      #pragma unroll
      for (int mt = 0; mt < 2; mt++) {
        int row = wid * 32 + mt * 16 + l16;
        int pos = row * 8 + ((cb + quad) ^ (row & 7));
        aF[mt] = *(const bf16x8*)&sA[cur][pos * 8];
      }
      #pragma unroll
      for (int nt = 0; nt < 4; nt++) {
        int row = nt * 16 + l16;
        int pos = row * 8 + ((cb + quad) ^ (row & 7));
        gF[nt] = *(const bf16x8*)&sBg[cur][pos * 8];
        uF[nt] = *(const bf16x8*)&sBu[cur][pos * 8];
      }
      #pragma unroll
      for (int mt = 0; mt < 2; mt++)
        #pragma unroll
        for (int nt = 0; nt < 4; nt++) {
          ag[mt][nt] = __builtin_amdgcn_mfma_f32_16x16x32_bf16(aF[mt], gF[nt], ag[mt][nt], 0, 0, 0);
          au[mt][nt] = __builtin_amdgcn_mfma_f32_16x16x32_bf16(aF[mt], uF[nt], au[mt][nt], 0, 0, 0);
        }
    }
    if (nxt) writeB(cur ^ 1);
    cur ^= 1;
  }
  #pragma unroll
  for (int mt = 0; mt < 2; mt++) {
    #pragma unroll
    for (int nt = 0; nt < 4; nt++) {
      #pragma unroll
      for (int r = 0; r < 4; r++) {
        int row_l = wid * 32 + mt * 16 + quad * 4 + r;
        int grow = m0 + row_l;
        if (grow < ne) {
          float g = ag[mt][nt][r], u = au[mt][nt][r];
          float hv = g / (1.f + __expf(-g)) * u;     // silu(g)*u
          hv *= wsl[e * T_TOK + grow];               // fold routing weight
          he[((size_t)e * T_TOK + grow) * MM + n0 + nt * 16 + l16] = f2bf(hv);
        }
      }
    }
  }
}

// ---------------------------------------------------------------------------
extern "C" void kernel_launch(void* const* d_in, const int* in_sizes, int n_in,
                              void* d_out, int out_size, void* d_ws, size_t ws_size,
                              hipStream_t stream) {
  (void)in_sizes; (void)n_in; (void)out_size; (void)ws_size;
  const float* hs     = (const float*)d_in[0];
  const float* cosp   = (const float*)d_in[1];
  const float* sinp   = (const float*)d_in[2];
  const float* ln1w   = (const float*)d_in[3];
  const float* wqkv   = (const float*)d_in[4];
  const float* qlw    = (const float*)d_in[5];
  const float* klw    = (const float*)d_in[6];
  const float* wdense = (const float*)d_in[7];
  const float* ln2w   = (const float*)d_in[8];
  const float* gw     = (const float*)d_in[9];
  const float* gbias  = (const float*)d_in[10];
  const float* weg    = (const float*)d_in[11];
  const float* weu    = (const float*)d_in[12];
  const float* wed    = (const float*)d_in[13];
  const float* wsg    = (const float*)d_in[14];
  const float* wsu    = (const float*)d_in[15];
  const float* wsd    = (const float*)d_in[16];
  float* out = (float*)d_out;

  char* ws = (char*)d_ws;
  size_t off = 0;
  auto alloc = [&](size_t b) { char* p = ws + off; off += (b + 255) & ~(size_t)255; return p; };
  __bf16* wbf   = (__bf16*)alloc((size_t)10485760 * 2);               // wqkv+wdense bf16
  __bf16* xb1   = (__bf16*)alloc((size_t)T_TOK * H_DIM * 2);
  __bf16* qreg  = (__bf16*)alloc((size_t)T_TOK * 3 * H_DIM * 2);      // qkv bf16 / buf
  __bf16* qb    = (__bf16*)alloc((size_t)2 * NH  * S_LEN * HD * 2);   // he span start
  __bf16* kb    = (__bf16*)alloc((size_t)2 * NKV * S_LEN * HD * 2);
  __bf16* vb    = (__bf16*)alloc((size_t)2 * NKV * S_LEN * HD * 2);
  __bf16* vt    = (__bf16*)alloc((size_t)2 * NKV * S_LEN * HD * 2);
  __bf16* outb  = (__bf16*)alloc((size_t)T_TOK * H_DIM * 2);
  __bf16* xb2   = (__bf16*)alloc((size_t)T_TOK * H_DIM * 2);
  int*    cnt   = (int*)   alloc(256);
  int*    list  = (int*)   alloc((size_t)9 * T_TOK * 4);
  float*  wsl   = (float*) alloc((size_t)9 * T_TOK * 4);
  signed char* jsl = (signed char*)alloc((size_t)9 * T_TOK);
  __bf16* qkvb  = qreg;            // [T, 3072] bf16 (dead after rope)
  __bf16* buf   = qreg;            // [T][3][H] bf16 contribs (same size)
  __bf16* he    = qb;              // 18.9 MB over dead qb..outb span (23 MB)

  const __bf16* wqkv_bf   = wbf;
  const __bf16* wdense_bf = wbf + 6291456;

  hipMemsetAsync(cnt, 0, 256, stream);
  // 0) qkv+dense weights fp32 -> bf16 (MoE weights convert in-GEMM now)
  wconv_k<<<2560, 256, 0, stream>>>(wqkv, wdense, wbf);
  // 1) x = rmsnorm(hidden, ln1_w) -> bf16
  rmsnorm_k<<<T_TOK, 256, 0, stream>>>(hs, ln1w, xb1);
  // 2) qkv = x @ w_qkv^T (bf16 out), 64x128 tiles -> 768 blocks (3/CU)
  gemm64_nt<0><<<dim3(QKV_O / 128, T_TOK / 64), 256, 0, stream>>>(
      xb1, wqkv_bf, nullptr, qkvb, nullptr, QKV_O, H_DIM);
  // 3) q/k norm + rope, v -> bf16 (b,h,s,d)
  rope_k<<<T_TOK * 6, 256, 0, stream>>>(qkvb, qlw, klw, cosp, sinp, qb, kb, vb);
  // 3b) vt = transpose(vb): [g][d][s]
  vtrans_k<<<dim3(16, 2, 8), 256, 0, stream>>>(vb, vt);
  // 4) flash attention -> outb bf16 (t, nh*hd)
  flash_k<<<dim3(S_LEN / 64, 2 * NH), 256, 0, stream>>>(qb, kb, vt, outb);
  // 5) hidden = hs + outb @ w_dense^T -> d_out, 64x128 tiles -> 512 blocks
  gemm64_nt<1><<<dim3(H_DIM / 128, T_TOK / 64), 256, 0, stream>>>(
      outb, wdense_bf, out, nullptr, hs, H_DIM, H_DIM);
  // 6) x2 = rmsnorm(hidden, ln2_w) -> bf16
  rmsnorm_k<<<T_TOK, 256, 0, stream>>>(out, ln2w, xb2);
  // 7) router v2 (256 thr/token, vectorized)
  router_k<<<T_TOK, 256, 0, stream>>>(out, ln2w, gw, gbias, cnt, list, wsl, jsl);
  // 8) gathered gate/up + silu-mul + weight fold -> he bf16 (fp32 B in-GEMM cvt)
  gemm_gateup<<<dim3(MM / 64, T_TOK / 128, 9), 256, 0, stream>>>(
      xb2, weg, weu, wsg, wsu, list, wsl, cnt, he);
  // 9) down-proj -> buf[t][j][:] (fp32 B in-GEMM cvt)
  gemm_down<<<dim3(H_DIM / 128, T_TOK / 128, 9), 256, 0, stream>>>(
      he, wed, wsd, buf, list, jsl, cnt);
  // 10) out[t] += buf[t][0] + buf[t][1] + buf[t][2]
  combine_k<<<T_TOK, 256, 0, stream>>>(buf, out);
}

// Round 6
// 487.470 us; speedup vs baseline: 1.0432x; 1.0432x over previous
//
#include <hip/hip_runtime.h>
#include <cstdint>
#include <cstddef>

#define T_TOK 2048
#define H_DIM 2048
#define S_LEN 1024
#define HD 128
#define NH 16
#define NKV 4
#define QKV_O 3072
#define MM 512
#define EPS 1e-6f
#define ATT_SCALE 0.08838834764831845f  // 128^-0.5

typedef __bf16 bf16x8 __attribute__((ext_vector_type(8)));
typedef __bf16 bf16x4 __attribute__((ext_vector_type(4)));
typedef float  f32x4  __attribute__((ext_vector_type(4)));

__device__ __forceinline__ __bf16 f2bf(float f) {
  unsigned u = __builtin_bit_cast(unsigned, f);
  u += 0x7fffu + ((u >> 16) & 1u);           // RNE; inputs are finite
  unsigned short h = (unsigned short)(u >> 16);
  return __builtin_bit_cast(__bf16, h);
}
__device__ __forceinline__ f32x4 fzero4() {
  f32x4 z; z[0] = 0.f; z[1] = 0.f; z[2] = 0.f; z[3] = 0.f; return z;
}
// async global->LDS, 16B per lane.
__device__ __forceinline__ void gld16(const __bf16* g, __bf16* l) {
  __builtin_amdgcn_global_load_lds(
      (const __attribute__((address_space(1))) unsigned int*)g,
      (__attribute__((address_space(3))) unsigned int*)l, 16, 0, 0);
}

// ---------------------------------------------------------------------------
// Weight fp32 -> bf16: ONLY wqkv + wdense. MoE weights convert in-GEMM.
// ---------------------------------------------------------------------------
__global__ __launch_bounds__(256) void wconv_k(
    const float* __restrict__ s0, const float* __restrict__ s1,
    __bf16* __restrict__ dst) {
  size_t e = ((size_t)blockIdx.x * 256 + threadIdx.x) * 16;
  const size_t E0 = 6291456;   // wqkv elems; then wdense
  const float* src; size_t base;
  if (e < E0) { src = s0; base = 0; }
  else        { src = s1; base = E0; }
  const float4* sp = (const float4*)(src + (e - base));
  float4 f0 = sp[0], f1 = sp[1], f2 = sp[2], f3 = sp[3];
  bf16x8 o0, o1;
  o0[0] = f2bf(f0.x); o0[1] = f2bf(f0.y); o0[2] = f2bf(f0.z); o0[3] = f2bf(f0.w);
  o0[4] = f2bf(f1.x); o0[5] = f2bf(f1.y); o0[6] = f2bf(f1.z); o0[7] = f2bf(f1.w);
  o1[0] = f2bf(f2.x); o1[1] = f2bf(f2.y); o1[2] = f2bf(f2.z); o1[3] = f2bf(f2.w);
  o1[4] = f2bf(f3.x); o1[5] = f2bf(f3.y); o1[6] = f2bf(f3.z); o1[7] = f2bf(f3.w);
  *(bf16x8*)(dst + e) = o0;
  *(bf16x8*)(dst + e + 8) = o1;
}

// ---------------------------------------------------------------------------
// RMSNorm over H=2048, fp32 in -> bf16 out. One block (256 thr) per token.
// ---------------------------------------------------------------------------
__global__ __launch_bounds__(256) void rmsnorm_k(const float* __restrict__ X,
                                                 const float* __restrict__ W,
                                                 __bf16* __restrict__ Y) {
  int t = blockIdx.x;
  int tid = threadIdx.x, lane = tid & 63, wid = tid >> 6;
  const float4* row = (const float4*)(X + (size_t)t * H_DIM);
  float4 v0 = row[tid], v1 = row[tid + 256];
  float ss = v0.x*v0.x + v0.y*v0.y + v0.z*v0.z + v0.w*v0.w
           + v1.x*v1.x + v1.y*v1.y + v1.z*v1.z + v1.w*v1.w;
  #pragma unroll
  for (int m = 1; m <= 32; m <<= 1) ss += __shfl_xor(ss, m, 64);
  __shared__ float red[4];
  if (lane == 0) red[wid] = ss;
  __syncthreads();
  float tot = red[0] + red[1] + red[2] + red[3];
  float sc = rsqrtf(tot * (1.f / H_DIM) + EPS);
  const float4* wp = (const float4*)W;
  float4 w0 = wp[tid], w1 = wp[tid + 256];
  bf16x4 o;
  o[0] = f2bf(v0.x*w0.x*sc); o[1] = f2bf(v0.y*w0.y*sc);
  o[2] = f2bf(v0.z*w0.z*sc); o[3] = f2bf(v0.w*w0.w*sc);
  *(bf16x4*)&Y[(size_t)t*H_DIM + tid*4] = o;
  o[0] = f2bf(v1.x*w1.x*sc); o[1] = f2bf(v1.y*w1.y*sc);
  o[2] = f2bf(v1.z*w1.z*sc); o[3] = f2bf(v1.w*w1.w*sc);
  *(bf16x4*)&Y[(size_t)t*H_DIM + 1024 + tid*4] = o;
}

// ---------------------------------------------------------------------------
// NT GEMM, 64(M) x 128(N) tile, BK=64, dbuf LDS, m97-style staging.
// MODE 0: OB bf16 plain store (ld N)            [qkv]
// MODE 1: C fp32 = acc + resid (ld 2048)        [dense + residual]
// ---------------------------------------------------------------------------
template<int MODE>
__global__ __launch_bounds__(256) void gemm64_nt(
    const __bf16* __restrict__ A, const __bf16* __restrict__ B,
    float* __restrict__ C, __bf16* __restrict__ OB,
    const float* __restrict__ resid, int N, int K) {
  int m0 = blockIdx.y * 64;
  int n0 = blockIdx.x * 128;
  __shared__ __bf16 sA[2][64 * 64];
  __shared__ __bf16 sB[2][128 * 64];
  int tid = threadIdx.x, lane = tid & 63, wid = tid >> 6;
  int quad = lane >> 4, l16 = lane & 15;
  int wm = wid & 1, wn = wid >> 1;

  const __bf16* gA[2]; const __bf16* gB[4];
  #pragma unroll
  for (int i = 0; i < 2; i++) {
    int p = tid + 256 * i;
    int row = p >> 3, sc = p & 7, gc = sc ^ (row & 7);
    gA[i] = A + (size_t)(m0 + row) * K + gc * 8;
  }
  #pragma unroll
  for (int i = 0; i < 4; i++) {
    int p = tid + 256 * i;
    int row = p >> 3, sc = p & 7, gc = sc ^ (row & 7);
    gB[i] = B + (size_t)(n0 + row) * K + gc * 8;
  }
  f32x4 acc[2][4];
  #pragma unroll
  for (int i = 0; i < 2; i++)
    #pragma unroll
    for (int j = 0; j < 4; j++) acc[i][j] = fzero4();

  auto stage = [&](int buf, int k0) {
    #pragma unroll
    for (int i = 0; i < 2; i++)
      gld16(gA[i] + k0, &sA[buf][(tid + 256 * i) * 8]);
    #pragma unroll
    for (int i = 0; i < 4; i++)
      gld16(gB[i] + k0, &sB[buf][(tid + 256 * i) * 8]);
  };
  stage(0, 0);
  int cur = 0;
  for (int k0 = 0; k0 < K; k0 += 64) {
    __syncthreads();
    if (k0 + 64 < K) stage(cur ^ 1, k0 + 64);
    #pragma unroll
    for (int ks = 0; ks < 64; ks += 32) {
      int cb = ks >> 3;
      bf16x8 aF[2], bF[4];
      #pragma unroll
      for (int mt = 0; mt < 2; mt++) {
        int row = wm * 32 + mt * 16 + l16;
        int pos = row * 8 + ((cb + quad) ^ (row & 7));
        aF[mt] = *(const bf16x8*)&sA[cur][pos * 8];
      }
      #pragma unroll
      for (int nt = 0; nt < 4; nt++) {
        int row = wn * 64 + nt * 16 + l16;
        int pos = row * 8 + ((cb + quad) ^ (row & 7));
        bF[nt] = *(const bf16x8*)&sB[cur][pos * 8];
      }
      #pragma unroll
      for (int mt = 0; mt < 2; mt++)
        #pragma unroll
        for (int nt = 0; nt < 4; nt++)
          acc[mt][nt] = __builtin_amdgcn_mfma_f32_16x16x32_bf16(
              aF[mt], bF[nt], acc[mt][nt], 0, 0, 0);
    }
    cur ^= 1;
  }
  #pragma unroll
  for (int mt = 0; mt < 2; mt++) {
    #pragma unroll
    for (int nt = 0; nt < 4; nt++) {
      #pragma unroll
      for (int r = 0; r < 4; r++) {
        int grow = m0 + wm*32 + mt*16 + quad*4 + r;
        int gcol = n0 + wn*64 + nt*16 + l16;
        float val = acc[mt][nt][r];
        if (MODE == 0) {
          OB[(size_t)grow * N + gcol] = f2bf(val);
        } else {
          C[(size_t)grow * H_DIM + gcol] = val + resid[(size_t)grow * H_DIM + gcol];
        }
      }
    }
  }
}

// ---------------------------------------------------------------------------
// Expert down-proj GEMM (128x128 tile, dbuf). B fp32 reg-staged with
// WRITE-LATE schedule (R5 fix): writeB happens after the NEXT barrier, one
// full iteration after its loadB -- HBM latency fully covered. Regs hold
// B[k0+64] during iteration k0.
// ---------------------------------------------------------------------------
__global__ __launch_bounds__(256) void gemm_down(
    const __bf16* __restrict__ A, const float* __restrict__ B,
    const float* __restrict__ B2, __bf16* __restrict__ OB,
    const int* __restrict__ list, const signed char* __restrict__ jsl,
    const int* __restrict__ cnt) {
  int e  = blockIdx.z;
  int ne = (e == 8) ? T_TOK : cnt[e];
  int m0 = blockIdx.y * 128;
  if (m0 >= ne) return;
  int n0 = blockIdx.x * 128;
  const __bf16* Ab = A + (size_t)e * T_TOK * MM;
  const float*  Bb = (e < 8) ? B + (size_t)e * H_DIM * MM : B2;
  const int K = MM;
  __shared__ __bf16 sA[2][128 * 64];
  __shared__ __bf16 sB[2][128 * 64];
  int tid = threadIdx.x, lane = tid & 63, wid = tid >> 6;
  int quad = lane >> 4, l16 = lane & 15;
  int wm = wid & 1, wn = wid >> 1;

  const __bf16* gA[4]; const float* gB[4];
  #pragma unroll
  for (int i = 0; i < 4; i++) {
    int p = tid + 256 * i;
    int row = p >> 3, sc = p & 7, gc = sc ^ (row & 7);
    gA[i] = Ab + (size_t)(m0 + row) * K + gc * 8;
    gB[i] = Bb + (size_t)(n0 + row) * K + gc * 8;
  }
  f32x4 acc[4][4];
  #pragma unroll
  for (int i = 0; i < 4; i++)
    #pragma unroll
    for (int j = 0; j < 4; j++) acc[i][j] = fzero4();

  f32x4 br[4][2];                       // fp32 B regs (32 VGPR)
  auto stageA = [&](int buf, int k0) {
    #pragma unroll
    for (int i = 0; i < 4; i++)
      gld16(gA[i] + k0, &sA[buf][(tid + 256 * i) * 8]);
  };
  auto loadB = [&](int k0) {
    #pragma unroll
    for (int i = 0; i < 4; i++) {
      br[i][0] = *(const f32x4*)(gB[i] + k0);
      br[i][1] = *(const f32x4*)(gB[i] + k0 + 4);
    }
  };
  auto writeB = [&](int buf) {
    #pragma unroll
    for (int i = 0; i < 4; i++) {
      int p = tid + 256 * i;
      bf16x8 o;
      #pragma unroll
      for (int j = 0; j < 4; j++) { o[j] = f2bf(br[i][0][j]); o[j+4] = f2bf(br[i][1][j]); }
      *(bf16x8*)&sB[buf][p * 8] = o;
    }
  };
  // prologue: buf0 <- B[0]; regs <- B[64]; A DMA for buf0.
  loadB(0); writeB(0); loadB(64); stageA(0, 0);
  int cur = 0;
  for (int k0 = 0; k0 < K; k0 += 64) {
    __syncthreads();                      // buf[cur] ready; regs arrived
    bool nxt = (k0 + 64 < K);
    if (nxt) {
      stageA(cur ^ 1, k0 + 64);           // A DMA for next
      writeB(cur ^ 1);                    // B[k0+64] from regs (loaded 1 iter ago)
      if (k0 + 128 < K) loadB(k0 + 128);  // refill regs for iter after next
    }
    #pragma unroll
    for (int ks = 0; ks < 64; ks += 32) {
      int cb = ks >> 3;
      bf16x8 aF[4], bF[4];
      #pragma unroll
      for (int mt = 0; mt < 4; mt++) {
        int row = wm * 64 + mt * 16 + l16;
        int pos = row * 8 + ((cb + quad) ^ (row & 7));
        aF[mt] = *(const bf16x8*)&sA[cur][pos * 8];
      }
      #pragma unroll
      for (int nt = 0; nt < 4; nt++) {
        int row = wn * 64 + nt * 16 + l16;
        int pos = row * 8 + ((cb + quad) ^ (row & 7));
        bF[nt] = *(const bf16x8*)&sB[cur][pos * 8];
      }
      #pragma unroll
      for (int mt = 0; mt < 4; mt++)
        #pragma unroll
        for (int nt = 0; nt < 4; nt++)
          acc[mt][nt] = __builtin_amdgcn_mfma_f32_16x16x32_bf16(
              aF[mt], bF[nt], acc[mt][nt], 0, 0, 0);
    }
    cur ^= 1;
  }
  #pragma unroll
  for (int mt = 0; mt < 4; mt++) {
    #pragma unroll
    for (int nt = 0; nt < 4; nt++) {
      #pragma unroll
      for (int r = 0; r < 4; r++) {
        int grow = m0 + wm*64 + mt*16 + quad*4 + r;
        int gcol = n0 + wn*64 + nt*16 + l16;
        if (grow < ne) {
          int tk = list[e * T_TOK + grow];
          int j  = (e == 8) ? 2 : (int)jsl[e * T_TOK + grow];
          OB[((size_t)tk * 3 + j) * H_DIM + gcol] = f2bf(acc[mt][nt][r]);
        }
      }
    }
  }
}

// ---------------------------------------------------------------------------
// Combine: out[t] += buf[t][0] + buf[t][1] + buf[t][2]  (bf16 contributions).
// ---------------------------------------------------------------------------
__global__ __launch_bounds__(256) void combine_k(const __bf16* __restrict__ buf,
                                                 float* __restrict__ out) {
  int t = blockIdx.x, tid = threadIdx.x;
  const __bf16* base = buf + (size_t)t * 3 * H_DIM;
  bf16x8 v0 = *(const bf16x8*)(base + tid * 8);
  bf16x8 v1 = *(const bf16x8*)(base + H_DIM + tid * 8);
  bf16x8 v2 = *(const bf16x8*)(base + 2 * H_DIM + tid * 8);
  float* o = out + (size_t)t * H_DIM + tid * 8;
  float4 a = *(float4*)o, b = *(float4*)(o + 4);
  a.x += (float)v0[0] + (float)v1[0] + (float)v2[0];
  a.y += (float)v0[1] + (float)v1[1] + (float)v2[1];
  a.z += (float)v0[2] + (float)v1[2] + (float)v2[2];
  a.w += (float)v0[3] + (float)v1[3] + (float)v2[3];
  b.x += (float)v0[4] + (float)v1[4] + (float)v2[4];
  b.y += (float)v0[5] + (float)v1[5] + (float)v2[5];
  b.z += (float)v0[6] + (float)v1[6] + (float)v2[6];
  b.w += (float)v0[7] + (float)v1[7] + (float)v2[7];
  *(float4*)o = a; *(float4*)(o + 4) = b;
}

// ---------------------------------------------------------------------------
// Per (token, head): q/k RMSNorm (HD=128) + RoPE, v passthrough; bf16 in/out.
// ---------------------------------------------------------------------------
__global__ __launch_bounds__(256) void rope_k(
    const __bf16* __restrict__ qkv, const float* __restrict__ qlw,
    const float* __restrict__ klw, const float* __restrict__ cosp,
    const float* __restrict__ sinp, __bf16* __restrict__ qb,
    __bf16* __restrict__ kb, __bf16* __restrict__ vb) {
  int bid = blockIdx.x;                 // T_TOK * 6
  int t = bid / 6;
  int head = (bid % 6) * 4 + (threadIdx.x >> 6);
  int b = t >> 10, s = t & 1023;
  int d = threadIdx.x & 63;
  const __bf16* src = qkv + (size_t)t * QKV_O + head * HD;
  float x1 = (float)src[d], x2 = (float)src[d + 64];
  if (head < 20) {
    float ssq = x1*x1 + x2*x2;
    #pragma unroll
    for (int m = 1; m <= 32; m <<= 1) ssq += __shfl_xor(ssq, m, 64);
    float sc = rsqrtf(ssq * (1.f / HD) + EPS);
    const float* w = (head < 16) ? qlw : klw;
    x1 = x1 * sc * w[d];
    x2 = x2 * sc * w[d + 64];
    size_t cb = (size_t)t * HD;
    float c1 = cosp[cb + d], s1 = sinp[cb + d];
    float c2 = cosp[cb + d + 64], s2 = sinp[cb + d + 64];
    float o1 = x1 * c1 - x2 * s1;
    float o2 = x2 * c2 + x1 * s2;
    if (head < 16) {
      __bf16* dst = qb + (((size_t)(b * NH + head)) * S_LEN + s) * HD;
      dst[d] = f2bf(o1); dst[d + 64] = f2bf(o2);
    } else {
      int kv = head - 16;
      __bf16* dst = kb + (((size_t)(b * NKV + kv)) * S_LEN + s) * HD;
      dst[d] = f2bf(o1); dst[d + 64] = f2bf(o2);
    }
  } else {
    int kv = head - 20;
    __bf16* dst = vb + (((size_t)(b * NKV + kv)) * S_LEN + s) * HD;
    dst[d] = src[d]; dst[d + 64] = src[d + 64];
  }
}

// ---------------------------------------------------------------------------
// V transpose: vb [g][s][d] -> vt [g][d][s]  (g = b*NKV+kv), 64x64 tiles.
// ---------------------------------------------------------------------------
__global__ __launch_bounds__(256) void vtrans_k(const __bf16* __restrict__ vb,
                                                __bf16* __restrict__ vt) {
  int s0 = blockIdx.x * 64, d0 = blockIdx.y * 64, g = blockIdx.z;
  __shared__ __bf16 sT[64 * 80];
  int tid = threadIdx.x;
  const __bf16* src = vb + (size_t)g * S_LEN * HD;
  #pragma unroll
  for (int i = 0; i < 2; i++) {
    int p = tid + 256 * i;
    int rs = p >> 3, cc = p & 7;
    bf16x8 v = *(const bf16x8*)(src + (size_t)(s0 + rs) * HD + d0 + cc * 8);
    #pragma unroll
    for (int j = 0; j < 8; j++) sT[(cc * 8 + j) * 80 + rs] = v[j];
  }
  __syncthreads();
  __bf16* dst = vt + (size_t)g * HD * S_LEN;
  #pragma unroll
  for (int i = 0; i < 2; i++) {
    int p = tid + 256 * i;
    int rd = p >> 3, cs = p & 7;
    bf16x8 v = *(const bf16x8*)&sT[rd * 80 + cs * 8];
    *(bf16x8*)(dst + (size_t)(d0 + rd) * S_LEN + s0 + cs * 8) = v;
  }
}

// ---------------------------------------------------------------------------
// Flash attention v2.
// ---------------------------------------------------------------------------
__global__ __launch_bounds__(256) void flash_k(
    const __bf16* __restrict__ qb, const __bf16* __restrict__ kb,
    const __bf16* __restrict__ vt, __bf16* __restrict__ outb) {
  int qt = blockIdx.x, bh = blockIdx.y;
  int b = bh >> 4, h = bh & 15, kv = h >> 2;
  int tid = threadIdx.x, lane = tid & 63, wid = tid >> 6;
  int quad = lane >> 4, l16 = lane & 15;
  __shared__ __bf16 sQ[64 * 128];
  __shared__ __bf16 sKP[64 * 128];
  __shared__ __bf16 sVt[128 * 64];
  __bf16* sK = sKP;
  __bf16* sP = sKP;

  const __bf16* qsrc = qb + (((size_t)(b * NH + h)) * S_LEN + qt * 64) * HD;
  #pragma unroll
  for (int i = 0; i < 4; i++) {
    int p = tid + 256 * i;
    int row = p >> 4, sc = p & 15, gc = sc ^ (row & 7);
    gld16(qsrc + (size_t)row * HD + gc * 8, &sQ[p * 8]);
  }
  const __bf16* kbase  = kb + ((size_t)(b * NKV + kv)) * S_LEN * HD;
  const __bf16* vtbase = vt + ((size_t)(b * NKV + kv)) * HD * S_LEN;
  const __bf16* gK[4]; const __bf16* gV[4];
  #pragma unroll
  for (int i = 0; i < 4; i++) {
    int p = tid + 256 * i;
    int rowk = p >> 4, sck = p & 15, gck = sck ^ (rowk & 7);
    gK[i] = kbase + (size_t)rowk * HD + gck * 8;
    int rowv = p >> 3, scv = p & 7, gcv = scv ^ (rowv & 7);
    gV[i] = vtbase + (size_t)rowv * S_LEN + gcv * 8;
  }
  float mrow[4], lrow[4];
  #pragma unroll
  for (int r = 0; r < 4; r++) { mrow[r] = -__builtin_inff(); lrow[r] = 0.f; }
  f32x4 accO[8];
  #pragma unroll
  for (int i = 0; i < 8; i++) accO[i] = fzero4();

  for (int kt = 0; kt < 16; kt++) {
    __syncthreads();
    #pragma unroll
    for (int i = 0; i < 4; i++) {
      gld16(gK[i] + (size_t)kt * 64 * HD, &sK[(tid + 256 * i) * 8]);
      gld16(gV[i] + kt * 64, &sVt[(tid + 256 * i) * 8]);
    }
    __syncthreads();
    f32x4 accS[4];
    #pragma unroll
    for (int jt = 0; jt < 4; jt++) accS[jt] = fzero4();
    int rowA = wid * 16 + l16;
    #pragma unroll
    for (int ks2 = 0; ks2 < 4; ks2++) {
      int posA = rowA * 16 + ((ks2 * 4 + quad) ^ (rowA & 7));
      bf16x8 aF = *(const bf16x8*)&sQ[posA * 8];
      #pragma unroll
      for (int jt = 0; jt < 4; jt++) {
        int rowB = jt * 16 + l16;
        int posB = rowB * 16 + ((ks2 * 4 + quad) ^ (rowB & 7));
        bf16x8 bF = *(const bf16x8*)&sK[posB * 8];
        accS[jt] = __builtin_amdgcn_mfma_f32_16x16x32_bf16(aF, bF, accS[jt], 0, 0, 0);
      }
    }
    float alpha[4];
    #pragma unroll
    for (int r = 0; r < 4; r++) {
      float mx = -__builtin_inff();
      #pragma unroll
      for (int jt = 0; jt < 4; jt++) {
        accS[jt][r] *= ATT_SCALE;
        mx = fmaxf(mx, accS[jt][r]);
      }
      #pragma unroll
      for (int m = 1; m <= 8; m <<= 1) mx = fmaxf(mx, __shfl_xor(mx, m, 64));
      float mn = fmaxf(mrow[r], mx);
      float al = __expf(mrow[r] - mn);
      float rs = 0.f;
      #pragma unroll
      for (int jt = 0; jt < 4; jt++) {
        float p = __expf(accS[jt][r] - mn);
        accS[jt][r] = p;
        rs += p;
      }
      #pragma unroll
      for (int m = 1; m <= 8; m <<= 1) rs += __shfl_xor(rs, m, 64);
      lrow[r] = lrow[r] * al + rs;
      mrow[r] = mn;
      alpha[r] = al;
    }
    #pragma unroll
    for (int nt = 0; nt < 8; nt++)
      #pragma unroll
      for (int r = 0; r < 4; r++) accO[nt][r] *= alpha[r];
    __syncthreads();
    #pragma unroll
    for (int jt = 0; jt < 4; jt++)
      #pragma unroll
      for (int r = 0; r < 4; r++)
        sP[(wid * 16 + quad * 4 + r) * 72 + jt * 16 + l16] = f2bf(accS[jt][r]);
    __syncthreads();
    #pragma unroll
    for (int ks2 = 0; ks2 < 2; ks2++) {
      bf16x8 aF = *(const bf16x8*)&sP[(wid * 16 + l16) * 72 + ks2 * 32 + quad * 8];
      #pragma unroll
      for (int nt = 0; nt < 8; nt++) {
        int rowB = nt * 16 + l16;
        int posB = rowB * 8 + ((ks2 * 4 + quad) ^ (rowB & 7));
        bf16x8 bF = *(const bf16x8*)&sVt[posB * 8];
        accO[nt] = __builtin_amdgcn_mfma_f32_16x16x32_bf16(aF, bF, accO[nt], 0, 0, 0);
      }
    }
  }
  #pragma unroll
  for (int nt = 0; nt < 8; nt++) {
    #pragma unroll
    for (int r = 0; r < 4; r++) {
      int srow = qt * 64 + wid * 16 + quad * 4 + r;
      float val = accO[nt][r] / lrow[r];
      outb[((size_t)(b * S_LEN + srow)) * H_DIM + h * HD + nt * 16 + l16] = f2bf(val);
    }
  }
}

// ---------------------------------------------------------------------------
// Router v2: 256 thr/token, float4-vectorized, wave+LDS reduce.
// ---------------------------------------------------------------------------
__global__ __launch_bounds__(256) void router_k(
    const float* __restrict__ hid, const float* __restrict__ ln2w,
    const float* __restrict__ gw, const float* __restrict__ gb,
    int* __restrict__ cnt, int* __restrict__ list, float* __restrict__ wsl,
    signed char* __restrict__ jsl) {
  int t = blockIdx.x;
  int tid = threadIdx.x, lane = tid & 63, wid = tid >> 6;
  const float4* row = (const float4*)(hid + (size_t)t * H_DIM);
  float4 v0 = row[tid], v1 = row[tid + 256];
  float ss = v0.x*v0.x + v0.y*v0.y + v0.z*v0.z + v0.w*v0.w
           + v1.x*v1.x + v1.y*v1.y + v1.z*v1.z + v1.w*v1.w;
  #pragma unroll
  for (int m = 1; m <= 32; m <<= 1) ss += __shfl_xor(ss, m, 64);
  __shared__ float red[4];
  __shared__ float lred[4][8];
  if (lane == 0) red[wid] = ss;
  __syncthreads();
  float tot = red[0] + red[1] + red[2] + red[3];
  float sc = rsqrtf(tot * (1.f / H_DIM) + EPS);
  const float4* wp = (const float4*)ln2w;
  float4 w0 = wp[tid], w1 = wp[tid + 256];
  float x0 = v0.x*w0.x*sc, x1 = v0.y*w0.y*sc, x2 = v0.z*w0.z*sc, x3 = v0.w*w0.w*sc;
  float x4 = v1.x*w1.x*sc, x5 = v1.y*w1.y*sc, x6 = v1.z*w1.z*sc, x7 = v1.w*w1.w*sc;
  float pe[8];
  #pragma unroll
  for (int e = 0; e < 8; e++) {
    const float4* gp = (const float4*)(gw + (size_t)e * H_DIM);
    float4 g0 = gp[tid], g1 = gp[tid + 256];
    float d = x0*g0.x + x1*g0.y + x2*g0.z + x3*g0.w
            + x4*g1.x + x5*g1.y + x6*g1.z + x7*g1.w;
    #pragma unroll
    for (int m = 1; m <= 32; m <<= 1) d += __shfl_xor(d, m, 64);
    pe[e] = d;
  }
  if (lane == 0) {
    #pragma unroll
    for (int e = 0; e < 8; e++) lred[wid][e] = pe[e];
  }
  __syncthreads();
  if (tid == 0) {
    float s[8], sb[8];
    #pragma unroll
    for (int e = 0; e < 8; e++) {
      float lg = lred[0][e] + lred[1][e] + lred[2][e] + lred[3][e];
      s[e] = 1.f / (1.f + __expf(-lg));
      sb[e] = s[e] + gb[e];
    }
    float gs[4];
    #pragma unroll
    for (int g = 0; g < 4; g++) gs[g] = sb[2 * g] + sb[2 * g + 1];
    int g1 = 0;
    for (int g = 1; g < 4; g++) if (gs[g] > gs[g1]) g1 = g;
    int g2 = -1;
    for (int g = 0; g < 4; g++) if (g != g1 && (g2 < 0 || gs[g] > gs[g2])) g2 = g;
    unsigned emask = (3u << (2 * g1)) | (3u << (2 * g2));
    int e1 = -1;
    for (int e = 0; e < 8; e++) if (((emask >> e) & 1u) && (e1 < 0 || sb[e] > sb[e1])) e1 = e;
    int e2 = -1;
    for (int e = 0; e < 8; e++) if (((emask >> e) & 1u) && e != e1 && (e2 < 0 || sb[e] > sb[e2])) e2 = e;
    float w1s = s[e1], w2s = s[e2];
    float dn = w1s + w2s + 1e-20f;
    w1s /= dn; w2s /= dn;   // RSF = 1.0
    int p1 = atomicAdd(&cnt[e1], 1);
    list[e1 * T_TOK + p1] = t; wsl[e1 * T_TOK + p1] = w1s; jsl[e1 * T_TOK + p1] = 0;
    int p2 = atomicAdd(&cnt[e2], 1);
    list[e2 * T_TOK + p2] = t; wsl[e2 * T_TOK + p2] = w2s; jsl[e2 * T_TOK + p2] = 1;
    list[8 * T_TOK + t] = t; wsl[8 * T_TOK + t] = 1.f;   // shared expert
  }
}

// ---------------------------------------------------------------------------
// Gathered gate+up GEMM, fused silu-mul + weight fold. B fp32 reg-staged,
// WRITE-LATE schedule (same fix as gemm_down).
// ---------------------------------------------------------------------------
__global__ __launch_bounds__(256) void gemm_gateup(
    const __bf16* __restrict__ X, const float* __restrict__ weg,
    const float* __restrict__ weu, const float* __restrict__ wsg,
    const float* __restrict__ wsu, const int* __restrict__ list,
    const float* __restrict__ wsl, const int* __restrict__ cnt,
    __bf16* __restrict__ he) {
  int e = blockIdx.z;
  int ne = (e == 8) ? T_TOK : cnt[e];
  int m0 = blockIdx.y * 128;
  if (m0 >= ne) return;
  int n0 = blockIdx.x * 64;
  const float* bg = (e < 8) ? weg + (size_t)e * MM * H_DIM : wsg;
  const float* bu = (e < 8) ? weu + (size_t)e * MM * H_DIM : wsu;
  const int* lst = list + e * T_TOK;
  __shared__ __bf16 sA[2][128 * 64];
  __shared__ __bf16 sBg[2][64 * 64];
  __shared__ __bf16 sBu[2][64 * 64];
  int tid = threadIdx.x, lane = tid & 63, wid = tid >> 6;
  int quad = lane >> 4, l16 = lane & 15;

  const __bf16* gA[4]; const float* gBg[2]; const float* gBu[2];
  #pragma unroll
  for (int i = 0; i < 4; i++) {
    int p = tid + 256 * i;
    int row = p >> 3, sc = p & 7, gc = sc ^ (row & 7);
    int r = m0 + row; if (r >= ne) r = ne - 1;
    int tk = lst[r];
    gA[i] = X + (size_t)tk * H_DIM + gc * 8;
  }
  #pragma unroll
  for (int i = 0; i < 2; i++) {
    int p = tid + 256 * i;
    int row = p >> 3, sc = p & 7, gc = sc ^ (row & 7);
    gBg[i] = bg + (size_t)(n0 + row) * H_DIM + gc * 8;
    gBu[i] = bu + (size_t)(n0 + row) * H_DIM + gc * 8;
  }
  f32x4 ag[2][4], au[2][4];
  #pragma unroll
  for (int i = 0; i < 2; i++)
    #pragma unroll
    for (int j = 0; j < 4; j++) { ag[i][j] = fzero4(); au[i][j] = fzero4(); }

  f32x4 bgr[2][2], bur[2][2];           // fp32 B regs (32 VGPR)
  auto stageA = [&](int buf, int k0) {
    #pragma unroll
    for (int i = 0; i < 4; i++)
      gld16(gA[i] + k0, &sA[buf][(tid + 256 * i) * 8]);
  };
  auto loadB = [&](int k0) {
    #pragma unroll
    for (int i = 0; i < 2; i++) {
      bgr[i][0] = *(const f32x4*)(gBg[i] + k0);
      bgr[i][1] = *(const f32x4*)(gBg[i] + k0 + 4);
      bur[i][0] = *(const f32x4*)(gBu[i] + k0);
      bur[i][1] = *(const f32x4*)(gBu[i] + k0 + 4);
    }
  };
  auto writeB = [&](int buf) {
    #pragma unroll
    for (int i = 0; i < 2; i++) {
      int p = tid + 256 * i;
      bf16x8 og, ou;
      #pragma unroll
      for (int j = 0; j < 4; j++) {
        og[j] = f2bf(bgr[i][0][j]); og[j+4] = f2bf(bgr[i][1][j]);
        ou[j] = f2bf(bur[i][0][j]); ou[j+4] = f2bf(bur[i][1][j]);
      }
      *(bf16x8*)&sBg[buf][p * 8] = og;
      *(bf16x8*)&sBu[buf][p * 8] = ou;
    }
  };
  // prologue: buf0 <- B[0]; regs <- B[64]; A DMA for buf0.
  loadB(0); writeB(0); loadB(64); stageA(0, 0);
  int cur = 0;
  for (int k0 = 0; k0 < H_DIM; k0 += 64) {
    __syncthreads();                       // buf[cur] ready; regs arrived
    bool nxt = (k0 + 64 < H_DIM);
    if (nxt) {
      stageA(cur ^ 1, k0 + 64);            // A DMA for next
      writeB(cur ^ 1);                     // B[k0+64] from regs (1 iter old)
      if (k0 + 128 < H_DIM) loadB(k0 + 128);
    }
    #pragma unroll
    for (int ks = 0; ks < 64; ks += 32) {
      int cb = ks >> 3;
      bf16x8 aF[2], gF[4], uF[4];
      #pragma unroll
      for (int mt = 0; mt < 2; mt++) {
        int row = wid * 32 + mt * 16 + l16;
        int pos = row * 8 + ((cb + quad) ^ (row & 7));
        aF[mt] = *(const bf16x8*)&sA[cur][pos * 8];
      }
      #pragma unroll
      for (int nt = 0; nt < 4; nt++) {
        int row = nt * 16 + l16;
        int pos = row * 8 + ((cb + quad) ^ (row & 7));
        gF[nt] = *(const bf16x8*)&sBg[cur][pos * 8];
        uF[nt] = *(const bf16x8*)&sBu[cur][pos * 8];
      }
      #pragma unroll
      for (int mt = 0; mt < 2; mt++)
        #pragma unroll
        for (int nt = 0; nt < 4; nt++) {
          ag[mt][nt] = __builtin_amdgcn_mfma_f32_16x16x32_bf16(aF[mt], gF[nt], ag[mt][nt], 0, 0, 0);
          au[mt][nt] = __builtin_amdgcn_mfma_f32_16x16x32_bf16(aF[mt], uF[nt], au[mt][nt], 0, 0, 0);
        }
    }
    cur ^= 1;
  }
  #pragma unroll
  for (int mt = 0; mt < 2; mt++) {
    #pragma unroll
    for (int nt = 0; nt < 4; nt++) {
      #pragma unroll
      for (int r = 0; r < 4; r++) {
        int row_l = wid * 32 + mt * 16 + quad * 4 + r;
        int grow = m0 + row_l;
        if (grow < ne) {
          float g = ag[mt][nt][r], u = au[mt][nt][r];
          float hv = g / (1.f + __expf(-g)) * u;     // silu(g)*u
          hv *= wsl[e * T_TOK + grow];               // fold routing weight
          he[((size_t)e * T_TOK + grow) * MM + n0 + nt * 16 + l16] = f2bf(hv);
        }
      }
    }
  }
}

// ---------------------------------------------------------------------------
extern "C" void kernel_launch(void* const* d_in, const int* in_sizes, int n_in,
                              void* d_out, int out_size, void* d_ws, size_t ws_size,
                              hipStream_t stream) {
  (void)in_sizes; (void)n_in; (void)out_size; (void)ws_size;
  const float* hs     = (const float*)d_in[0];
  const float* cosp   = (const float*)d_in[1];
  const float* sinp   = (const float*)d_in[2];
  const float* ln1w   = (const float*)d_in[3];
  const float* wqkv   = (const float*)d_in[4];
  const float* qlw    = (const float*)d_in[5];
  const float* klw    = (const float*)d_in[6];
  const float* wdense = (const float*)d_in[7];
  const float* ln2w   = (const float*)d_in[8];
  const float* gw     = (const float*)d_in[9];
  const float* gbias  = (const float*)d_in[10];
  const float* weg    = (const float*)d_in[11];
  const float* weu    = (const float*)d_in[12];
  const float* wed    = (const float*)d_in[13];
  const float* wsg    = (const float*)d_in[14];
  const float* wsu    = (const float*)d_in[15];
  const float* wsd    = (const float*)d_in[16];
  float* out = (float*)d_out;

  char* ws = (char*)d_ws;
  size_t off = 0;
  auto alloc = [&](size_t b) { char* p = ws + off; off += (b + 255) & ~(size_t)255; return p; };
  __bf16* wbf   = (__bf16*)alloc((size_t)10485760 * 2);               // wqkv+wdense bf16
  __bf16* xb1   = (__bf16*)alloc((size_t)T_TOK * H_DIM * 2);
  __bf16* qreg  = (__bf16*)alloc((size_t)T_TOK * 3 * H_DIM * 2);      // qkv bf16 / buf
  __bf16* qb    = (__bf16*)alloc((size_t)2 * NH  * S_LEN * HD * 2);   // he span start
  __bf16* kb    = (__bf16*)alloc((size_t)2 * NKV * S_LEN * HD * 2);
  __bf16* vb    = (__bf16*)alloc((size_t)2 * NKV * S_LEN * HD * 2);
  __bf16* vt    = (__bf16*)alloc((size_t)2 * NKV * S_LEN * HD * 2);
  __bf16* outb  = (__bf16*)alloc((size_t)T_TOK * H_DIM * 2);
  __bf16* xb2   = (__bf16*)alloc((size_t)T_TOK * H_DIM * 2);
  int*    cnt   = (int*)   alloc(256);
  int*    list  = (int*)   alloc((size_t)9 * T_TOK * 4);
  float*  wsl   = (float*) alloc((size_t)9 * T_TOK * 4);
  signed char* jsl = (signed char*)alloc((size_t)9 * T_TOK);
  __bf16* qkvb  = qreg;            // [T, 3072] bf16 (dead after rope)
  __bf16* buf   = qreg;            // [T][3][H] bf16 contribs (same size)
  __bf16* he    = qb;              // 18.9 MB over dead qb..outb span (23 MB)

  const __bf16* wqkv_bf   = wbf;
  const __bf16* wdense_bf = wbf + 6291456;

  hipMemsetAsync(cnt, 0, 256, stream);
  // 0) qkv+dense weights fp32 -> bf16
  wconv_k<<<2560, 256, 0, stream>>>(wqkv, wdense, wbf);
  // 1) x = rmsnorm(hidden, ln1_w) -> bf16
  rmsnorm_k<<<T_TOK, 256, 0, stream>>>(hs, ln1w, xb1);
  // 2) qkv = x @ w_qkv^T (bf16 out)
  gemm64_nt<0><<<dim3(QKV_O / 128, T_TOK / 64), 256, 0, stream>>>(
      xb1, wqkv_bf, nullptr, qkvb, nullptr, QKV_O, H_DIM);
  // 3) q/k norm + rope, v -> bf16 (b,h,s,d)
  rope_k<<<T_TOK * 6, 256, 0, stream>>>(qkvb, qlw, klw, cosp, sinp, qb, kb, vb);
  // 3b) vt = transpose(vb): [g][d][s]
  vtrans_k<<<dim3(16, 2, 8), 256, 0, stream>>>(vb, vt);
  // 4) flash attention -> outb bf16 (t, nh*hd)
  flash_k<<<dim3(S_LEN / 64, 2 * NH), 256, 0, stream>>>(qb, kb, vt, outb);
  // 5) hidden = hs + outb @ w_dense^T -> d_out
  gemm64_nt<1><<<dim3(H_DIM / 128, T_TOK / 64), 256, 0, stream>>>(
      outb, wdense_bf, out, nullptr, hs, H_DIM, H_DIM);
  // 6) x2 = rmsnorm(hidden, ln2_w) -> bf16
  rmsnorm_k<<<T_TOK, 256, 0, stream>>>(out, ln2w, xb2);
  // 7) router v2
  router_k<<<T_TOK, 256, 0, stream>>>(out, ln2w, gw, gbias, cnt, list, wsl, jsl);
  // 8) gathered gate/up + silu-mul + weight fold -> he bf16 (write-late fp32 B)
  gemm_gateup<<<dim3(MM / 64, T_TOK / 128, 9), 256, 0, stream>>>(
      xb2, weg, weu, wsg, wsu, list, wsl, cnt, he);
  // 9) down-proj -> buf[t][j][:] (write-late fp32 B)
  gemm_down<<<dim3(H_DIM / 128, T_TOK / 128, 9), 256, 0, stream>>>(
      he, wed, wsd, buf, list, jsl, cnt);
  // 10) out[t] += buf[t][0] + buf[t][1] + buf[t][2]
  combine_k<<<T_TOK, 256, 0, stream>>>(buf, out);
}